// Round 1
// baseline (158.763 us; speedup 1.0000x reference)
//
#include <hip/hip_runtime.h>
#include <math.h>

// Problem constants (match reference)
#define DD      3
#define HID     128
#define NOUT    9            // prod(out_shape)
#define N_ROWS_C 60000
#define NEDGE   960000
#define NGROUP  (NEDGE / DD)     // 320000
#define YSTRIDE 24               // padded row stride in floats (96 B, 16B-aligned halves)

// ---------------------------------------------------------------------------
// Kernel 1: per node-row i:
//   y[i][0..8]   = dot(x[i][0:128],  W[j][0:128])    (j = 0..8)
//   y[i][12..20] = dot(x[i][0:128],  W[j][128:256])
// W layout: [9][256] row-major (nn.Linear weight [out, in]).
// One row per thread; W addresses are wave-uniform -> scalar loads expected.
// ---------------------------------------------------------------------------
__global__ __launch_bounds__(256) void precompute_y(
    const float* __restrict__ x, const float* __restrict__ W, float* __restrict__ y)
{
    int i = blockIdx.x * 256 + threadIdx.x;
    if (i >= N_ROWS_C) return;

    const float4* __restrict__ xv = reinterpret_cast<const float4*>(x) + (size_t)i * 32;
    const float4* __restrict__ Wv = reinterpret_cast<const float4*>(W);  // each W row = 64 float4

    float accL[NOUT], accR[NOUT];
#pragma unroll
    for (int j = 0; j < NOUT; ++j) { accL[j] = 0.f; accR[j] = 0.f; }

#pragma unroll 4
    for (int q = 0; q < 32; ++q) {           // 32 float4 = 128 floats of x[i]
        float4 xq = xv[q];
#pragma unroll
        for (int j = 0; j < NOUT; ++j) {
            float4 wl = Wv[j * 64 + q];       // left half  (k = 0..127)
            float4 wr = Wv[j * 64 + 32 + q];  // right half (k = 128..255)
            accL[j] += xq.x * wl.x + xq.y * wl.y + xq.z * wl.z + xq.w * wl.w;
            accR[j] += xq.x * wr.x + xq.y * wr.y + xq.z * wr.z + xq.w * wr.w;
        }
    }

    float* yr = y + (size_t)i * YSTRIDE;
    reinterpret_cast<float4*>(yr)[0] = make_float4(accL[0], accL[1], accL[2], accL[3]);
    reinterpret_cast<float4*>(yr)[1] = make_float4(accL[4], accL[5], accL[6], accL[7]);
    yr[8] = accL[8];
    reinterpret_cast<float4*>(yr + 12)[0] = make_float4(accR[0], accR[1], accR[2], accR[3]);
    reinterpret_cast<float4*>(yr + 12)[1] = make_float4(accR[4], accR[5], accR[6], accR[7]);
    yr[20] = accR[8];
}

// ---------------------------------------------------------------------------
// Kernel 2: per group g (3 consecutive edges):
//   out[g][j] = tanh( sum_{e in group} yL[row_e][j] + yR[col_e][j] )
// Indices staged coalesced via LDS; output staged via LDS for coalesced store.
// NGROUP = 320000 = 1250 * 256 exactly -> no tail guards needed.
// ---------------------------------------------------------------------------
__global__ __launch_bounds__(256) void gather_tanh(
    const int* __restrict__ eidx, const float* __restrict__ y, float* __restrict__ out)
{
    __shared__ int   sRow[3 * 256];
    __shared__ int   sCol[3 * 256];
    __shared__ float sOut[NOUT * 256];

    const int t  = threadIdx.x;
    const int g0 = blockIdx.x * 256;
    const int e0 = g0 * 3;

    // coalesced index loads: 3 per thread for row, 3 for col
#pragma unroll
    for (int p = 0; p < 3; ++p) {
        int e = e0 + t + p * 256;
        sRow[t + p * 256] = eidx[e];
        sCol[t + p * 256] = eidx[NEDGE + e];
    }
    __syncthreads();

    float4 A = make_float4(0.f, 0.f, 0.f, 0.f);
    float4 B = make_float4(0.f, 0.f, 0.f, 0.f);
    float  c = 0.f;

#pragma unroll
    for (int p = 0; p < 3; ++p) {
        {
            const float* r = y + (size_t)sRow[3 * t + p] * YSTRIDE;       // left half
            float4 a = reinterpret_cast<const float4*>(r)[0];
            float4 b = reinterpret_cast<const float4*>(r)[1];
            A.x += a.x; A.y += a.y; A.z += a.z; A.w += a.w;
            B.x += b.x; B.y += b.y; B.z += b.z; B.w += b.w;
            c += r[8];
        }
        {
            const float* r = y + (size_t)sCol[3 * t + p] * YSTRIDE + 12;  // right half
            float4 a = reinterpret_cast<const float4*>(r)[0];
            float4 b = reinterpret_cast<const float4*>(r)[1];
            A.x += a.x; A.y += a.y; A.z += a.z; A.w += a.w;
            B.x += b.x; B.y += b.y; B.z += b.z; B.w += b.w;
            c += r[8];
        }
    }

    sOut[t * NOUT + 0] = tanhf(A.x);
    sOut[t * NOUT + 1] = tanhf(A.y);
    sOut[t * NOUT + 2] = tanhf(A.z);
    sOut[t * NOUT + 3] = tanhf(A.w);
    sOut[t * NOUT + 4] = tanhf(B.x);
    sOut[t * NOUT + 5] = tanhf(B.y);
    sOut[t * NOUT + 6] = tanhf(B.z);
    sOut[t * NOUT + 7] = tanhf(B.w);
    sOut[t * NOUT + 8] = tanhf(c);
    __syncthreads();

    // coalesced store of this block's 2304 contiguous floats
    float* o = out + (size_t)g0 * NOUT;
#pragma unroll
    for (int j = 0; j < NOUT; ++j) {
        o[t + 256 * j] = sOut[t + 256 * j];
    }
}

extern "C" void kernel_launch(void* const* d_in, const int* in_sizes, int n_in,
                              void* d_out, int out_size, void* d_ws, size_t ws_size,
                              hipStream_t stream) {
    const float* x    = (const float*)d_in[0];   // [60000, 128] fp32
    const float* W    = (const float*)d_in[1];   // [9, 256] fp32
    const int*   eidx = (const int*)d_in[2];     // [2, 960000] int
    float*       out  = (float*)d_out;           // [320000, 9] fp32
    float*       y    = (float*)d_ws;            // [60000, 24] fp32 scratch (5.76 MB)

    precompute_y<<<(N_ROWS_C + 255) / 256, 256, 0, stream>>>(x, W, y);
    gather_tanh<<<NGROUP / 256, 256, 0, stream>>>(eidx, y, out);
}

// Round 3
// 109.055 us; speedup vs baseline: 1.4558x; 1.4558x over previous
//
#include <hip/hip_runtime.h>
#include <math.h>

// Problem constants (match reference)
#define DD       3
#define HID      128
#define NOUT     9             // prod(out_shape)
#define N_ROWS_C 60000
#define NEDGE    960000
#define NGROUP   (NEDGE / DD)  // 320000
#define YSTRIDE  24            // padded row stride in floats (96 B)

// ---------------------------------------------------------------------------
// DPP butterfly reduction over aligned 8-lane groups (masks {1,2,7}).
// quad_perm(1,0,3,2)=0xB1 -> xor1; quad_perm(2,3,0,1)=0x4E -> xor2;
// row_half_mirror=0x141 -> xor7.  Pure VALU, no LDS traffic.
// ---------------------------------------------------------------------------
template <int CTRL>
__device__ __forceinline__ float dpp_xor_add(float v) {
    int r = __builtin_amdgcn_update_dpp(0, __float_as_int(v), CTRL, 0xf, 0xf, true);
    return v + __int_as_float(r);
}
__device__ __forceinline__ float red8(float v) {
    v = dpp_xor_add<0xB1>(v);   // xor 1
    v = dpp_xor_add<0x4E>(v);   // xor 2
    v = dpp_xor_add<0x141>(v);  // xor 7
    return v;
}

// fast tanh: tanh(v) = 1 - 2/(1+e^{2v});  e^{2v} = 2^(2*log2(e)*v)
// v_exp_f32 computes 2^x -> builtin is __builtin_amdgcn_exp2f.
__device__ __forceinline__ float fast_tanh(float v) {
    float e = __builtin_amdgcn_exp2f(v * 2.8853900817779268f);
    return 1.0f - 2.0f * __builtin_amdgcn_rcpf(e + 1.0f);
}

// ---------------------------------------------------------------------------
// Kernel 1: y[i][0..8] = x[i] . W[j][0:128], y[i][12..20] = x[i] . W[j][128:256]
// 8 lanes per row (k-split, 16 floats each), 2 rows per lane (r and r+32).
// W staged in LDS (9 KB); per-instr LDS reads hit all 32 banks, 8-way broadcast.
// Block = 256 threads covers 64 rows; grid = ceil(60000/64) = 938.
// ---------------------------------------------------------------------------
__global__ __launch_bounds__(256) void precompute_y(
    const float* __restrict__ x, const float* __restrict__ W, float* __restrict__ y)
{
    __shared__ float4 sW[576];               // 9 rows x 64 float4
    const int t = threadIdx.x;
    const float4* __restrict__ Wv = reinterpret_cast<const float4*>(W);
    for (int i = t; i < 576; i += 256) sW[i] = Wv[i];

    const int s    = t & 7;                  // k-subchunk
    const int slot = t >> 3;                 // row slot 0..31
    const int base = blockIdx.x * 64;
    const int r0   = base + slot;            // always < 60000 (base max 59968)
    const int r1   = base + 32 + slot;
    const int r1c  = (r1 < N_ROWS_C) ? r1 : 0;

    __syncthreads();

    const float4* __restrict__ xv = reinterpret_cast<const float4*>(x);

    float aL0[NOUT], aR0[NOUT], aL1[NOUT], aR1[NOUT];
#pragma unroll
    for (int j = 0; j < NOUT; ++j) { aL0[j] = 0.f; aR0[j] = 0.f; aL1[j] = 0.f; aR1[j] = 0.f; }

#pragma unroll
    for (int q = 0; q < 4; ++q) {
        const int f = s + 8 * q;             // float4 index 0..31 within row
        float4 x0 = xv[(size_t)r0  * 32 + f];
        float4 x1 = xv[(size_t)r1c * 32 + f];
#pragma unroll
        for (int j = 0; j < NOUT; ++j) {
            float4 wl = sW[j * 64 + f];       // left half  (k 0..127)
            float4 wr = sW[j * 64 + 32 + f];  // right half (k 128..255)
            aL0[j] += x0.x * wl.x + x0.y * wl.y + x0.z * wl.z + x0.w * wl.w;
            aR0[j] += x0.x * wr.x + x0.y * wr.y + x0.z * wr.z + x0.w * wr.w;
            aL1[j] += x1.x * wl.x + x1.y * wl.y + x1.z * wl.z + x1.w * wl.w;
            aR1[j] += x1.x * wr.x + x1.y * wr.y + x1.z * wr.z + x1.w * wr.w;
        }
    }

#pragma unroll
    for (int j = 0; j < NOUT; ++j) {
        aL0[j] = red8(aL0[j]); aR0[j] = red8(aR0[j]);
        aL1[j] = red8(aL1[j]); aR1[j] = red8(aR1[j]);
    }

    // after butterfly every lane holds the totals; lane 0 stores row r0, lane 1 row r1
    if (s == 0) {
        float* yr = y + (size_t)r0 * YSTRIDE;
        reinterpret_cast<float4*>(yr)[0]      = make_float4(aL0[0], aL0[1], aL0[2], aL0[3]);
        reinterpret_cast<float4*>(yr)[1]      = make_float4(aL0[4], aL0[5], aL0[6], aL0[7]);
        yr[8]  = aL0[8];
        reinterpret_cast<float4*>(yr + 12)[0] = make_float4(aR0[0], aR0[1], aR0[2], aR0[3]);
        reinterpret_cast<float4*>(yr + 12)[1] = make_float4(aR0[4], aR0[5], aR0[6], aR0[7]);
        yr[20] = aR0[8];
    } else if (s == 1 && r1 < N_ROWS_C) {
        float* yr = y + (size_t)r1 * YSTRIDE;
        reinterpret_cast<float4*>(yr)[0]      = make_float4(aL1[0], aL1[1], aL1[2], aL1[3]);
        reinterpret_cast<float4*>(yr)[1]      = make_float4(aL1[4], aL1[5], aL1[6], aL1[7]);
        yr[8]  = aL1[8];
        reinterpret_cast<float4*>(yr + 12)[0] = make_float4(aR1[0], aR1[1], aR1[2], aR1[3]);
        reinterpret_cast<float4*>(yr + 12)[1] = make_float4(aR1[4], aR1[5], aR1[6], aR1[7]);
        yr[20] = aR1[8];
    }
}

// ---------------------------------------------------------------------------
// Kernel 2: per group g (3 consecutive edges):
//   out[g][j] = tanh( sum_{e in group} yL[row_e][j] + yR[col_e][j] )
// ---------------------------------------------------------------------------
__global__ __launch_bounds__(256) void gather_tanh(
    const int* __restrict__ eidx, const float* __restrict__ y, float* __restrict__ out)
{
    __shared__ int   sRow[3 * 256];
    __shared__ int   sCol[3 * 256];
    __shared__ float sOut[NOUT * 256];

    const int t  = threadIdx.x;
    const int g0 = blockIdx.x * 256;
    const int e0 = g0 * 3;

#pragma unroll
    for (int p = 0; p < 3; ++p) {
        int e = e0 + t + p * 256;
        sRow[t + p * 256] = eidx[e];
        sCol[t + p * 256] = eidx[NEDGE + e];
    }
    __syncthreads();

    float4 A = make_float4(0.f, 0.f, 0.f, 0.f);
    float4 B = make_float4(0.f, 0.f, 0.f, 0.f);
    float  c = 0.f;

#pragma unroll
    for (int p = 0; p < 3; ++p) {
        {
            const float* r = y + (size_t)sRow[3 * t + p] * YSTRIDE;       // left half
            float4 a = reinterpret_cast<const float4*>(r)[0];
            float4 b = reinterpret_cast<const float4*>(r)[1];
            A.x += a.x; A.y += a.y; A.z += a.z; A.w += a.w;
            B.x += b.x; B.y += b.y; B.z += b.z; B.w += b.w;
            c += r[8];
        }
        {
            const float* r = y + (size_t)sCol[3 * t + p] * YSTRIDE + 12;  // right half
            float4 a = reinterpret_cast<const float4*>(r)[0];
            float4 b = reinterpret_cast<const float4*>(r)[1];
            A.x += a.x; A.y += a.y; A.z += a.z; A.w += a.w;
            B.x += b.x; B.y += b.y; B.z += b.z; B.w += b.w;
            c += r[8];
        }
    }

    sOut[t * NOUT + 0] = fast_tanh(A.x);
    sOut[t * NOUT + 1] = fast_tanh(A.y);
    sOut[t * NOUT + 2] = fast_tanh(A.z);
    sOut[t * NOUT + 3] = fast_tanh(A.w);
    sOut[t * NOUT + 4] = fast_tanh(B.x);
    sOut[t * NOUT + 5] = fast_tanh(B.y);
    sOut[t * NOUT + 6] = fast_tanh(B.z);
    sOut[t * NOUT + 7] = fast_tanh(B.w);
    sOut[t * NOUT + 8] = fast_tanh(c);
    __syncthreads();

    float* o = out + (size_t)g0 * NOUT;
#pragma unroll
    for (int j = 0; j < NOUT; ++j) {
        o[t + 256 * j] = sOut[t + 256 * j];
    }
}

extern "C" void kernel_launch(void* const* d_in, const int* in_sizes, int n_in,
                              void* d_out, int out_size, void* d_ws, size_t ws_size,
                              hipStream_t stream) {
    const float* x    = (const float*)d_in[0];   // [60000, 128] fp32
    const float* W    = (const float*)d_in[1];   // [9, 256] fp32
    const int*   eidx = (const int*)d_in[2];     // [2, 960000] int32
    float*       out  = (float*)d_out;           // [320000, 9] fp32
    float*       y    = (float*)d_ws;            // [60000, 24] fp32 scratch (5.76 MB)

    precompute_y<<<(N_ROWS_C + 63) / 64, 256, 0, stream>>>(x, W, y);
    gather_tanh<<<NGROUP / 256, 256, 0, stream>>>(eidx, y, out);
}

// Round 4
// 105.276 us; speedup vs baseline: 1.5081x; 1.0359x over previous
//
#include <hip/hip_runtime.h>
#include <hip/hip_fp16.h>
#include <math.h>

// Problem constants (match reference)
#define DD       3
#define HID      128
#define NOUT     9             // prod(out_shape)
#define N_ROWS_C 60000
#define NEDGE    960000
#define NGROUP   (NEDGE / DD)  // 320000
#define YH_STRIDE 32           // halves per y row = 64 B = exactly one cache line
// y row layout (halves): [0..8]=L0..L8, [9..15]=pad, [16..24]=R0..R8, [25..31]=pad

// ---------------------------------------------------------------------------
// DPP butterfly reduction over aligned 8-lane groups (masks {1,2,7}).
// ---------------------------------------------------------------------------
template <int CTRL>
__device__ __forceinline__ float dpp_xor_add(float v) {
    int r = __builtin_amdgcn_update_dpp(0, __float_as_int(v), CTRL, 0xf, 0xf, true);
    return v + __int_as_float(r);
}
__device__ __forceinline__ float red8(float v) {
    v = dpp_xor_add<0xB1>(v);   // xor 1 (quad_perm 1,0,3,2)
    v = dpp_xor_add<0x4E>(v);   // xor 2 (quad_perm 2,3,0,1)
    v = dpp_xor_add<0x141>(v);  // xor 7 (row_half_mirror)
    return v;
}

// fast tanh: tanh(v) = 1 - 2/(1+e^{2v});  v_exp_f32 computes 2^x
__device__ __forceinline__ float fast_tanh(float v) {
    float e = __builtin_amdgcn_exp2f(v * 2.8853900817779268f);
    return 1.0f - 2.0f * __builtin_amdgcn_rcpf(e + 1.0f);
}

__device__ __forceinline__ unsigned int pk(float a, float b) {
    __half2 h = __floats2half2_rn(a, b);
    return *reinterpret_cast<unsigned int*>(&h);
}

// ---------------------------------------------------------------------------
// Kernel 1: y[i] row = fp16-packed [ x[i].W[j][0:128] (j=0..8) | x[i].W[j][128:256] ]
// 8 lanes per row (k-split, 16 floats each), 2 rows per lane (r and r+32).
// W staged in LDS (9 KB); conflict-free (8 distinct float4 -> 32 banks, 8-way bcast).
// Block = 256 threads covers 64 rows; grid = ceil(60000/64) = 938.
// ---------------------------------------------------------------------------
__global__ __launch_bounds__(256) void precompute_y(
    const float* __restrict__ x, const float* __restrict__ W, __half* __restrict__ yh)
{
    __shared__ float4 sW[576];               // 9 rows x 64 float4
    const int t = threadIdx.x;
    const float4* __restrict__ Wv = reinterpret_cast<const float4*>(W);
    for (int i = t; i < 576; i += 256) sW[i] = Wv[i];

    const int s    = t & 7;                  // k-subchunk
    const int slot = t >> 3;                 // row slot 0..31
    const int base = blockIdx.x * 64;
    const int r0   = base + slot;            // base max 59968 -> always < 60000
    const int r1   = base + 32 + slot;
    const int r1c  = (r1 < N_ROWS_C) ? r1 : 0;

    __syncthreads();

    const float4* __restrict__ xv = reinterpret_cast<const float4*>(x);

    float aL0[NOUT], aR0[NOUT], aL1[NOUT], aR1[NOUT];
#pragma unroll
    for (int j = 0; j < NOUT; ++j) { aL0[j] = 0.f; aR0[j] = 0.f; aL1[j] = 0.f; aR1[j] = 0.f; }

#pragma unroll
    for (int q = 0; q < 4; ++q) {
        const int f = s + 8 * q;             // float4 index 0..31 within row
        float4 x0 = xv[(size_t)r0  * 32 + f];
        float4 x1 = xv[(size_t)r1c * 32 + f];
#pragma unroll
        for (int j = 0; j < NOUT; ++j) {
            float4 wl = sW[j * 64 + f];       // left half  (k 0..127)
            float4 wr = sW[j * 64 + 32 + f];  // right half (k 128..255)
            aL0[j] += x0.x * wl.x + x0.y * wl.y + x0.z * wl.z + x0.w * wl.w;
            aR0[j] += x0.x * wr.x + x0.y * wr.y + x0.z * wr.z + x0.w * wr.w;
            aL1[j] += x1.x * wl.x + x1.y * wl.y + x1.z * wl.z + x1.w * wl.w;
            aR1[j] += x1.x * wr.x + x1.y * wr.y + x1.z * wr.z + x1.w * wr.w;
        }
    }

#pragma unroll
    for (int j = 0; j < NOUT; ++j) {
        aL0[j] = red8(aL0[j]); aR0[j] = red8(aR0[j]);
        aL1[j] = red8(aL1[j]); aR1[j] = red8(aR1[j]);
    }

    if (s == 0) {
        __half* yr = yh + (size_t)r0 * YH_STRIDE;
        *reinterpret_cast<uint4*>(yr) =
            make_uint4(pk(aL0[0],aL0[1]), pk(aL0[2],aL0[3]), pk(aL0[4],aL0[5]), pk(aL0[6],aL0[7]));
        *reinterpret_cast<uint2*>(yr + 8)  = make_uint2(pk(aL0[8], 0.f), 0u);
        *reinterpret_cast<uint4*>(yr + 16) =
            make_uint4(pk(aR0[0],aR0[1]), pk(aR0[2],aR0[3]), pk(aR0[4],aR0[5]), pk(aR0[6],aR0[7]));
        *reinterpret_cast<uint2*>(yr + 24) = make_uint2(pk(aR0[8], 0.f), 0u);
    } else if (s == 1 && r1 < N_ROWS_C) {
        __half* yr = yh + (size_t)r1 * YH_STRIDE;
        *reinterpret_cast<uint4*>(yr) =
            make_uint4(pk(aL1[0],aL1[1]), pk(aL1[2],aL1[3]), pk(aL1[4],aL1[5]), pk(aL1[6],aL1[7]));
        *reinterpret_cast<uint2*>(yr + 8)  = make_uint2(pk(aL1[8], 0.f), 0u);
        *reinterpret_cast<uint4*>(yr + 16) =
            make_uint4(pk(aR1[0],aR1[1]), pk(aR1[2],aR1[3]), pk(aR1[4],aR1[5]), pk(aR1[6],aR1[7]));
        *reinterpret_cast<uint2*>(yr + 24) = make_uint2(pk(aR1[8], 0.f), 0u);
    }
}

// ---------------------------------------------------------------------------
// Kernel 2: out[g][j] = tanh( sum_{e in group g} yL[row_e][j] + yR[col_e][j] )
// fp16 y, one aligned 64 B line per node-row; 2 loads per half-row gather.
// ---------------------------------------------------------------------------
__device__ __forceinline__ void acc9(float* a, uint4 v, unsigned int v4) {
    float2 f;
    f = __half22float2(*reinterpret_cast<__half2*>(&v.x)); a[0] += f.x; a[1] += f.y;
    f = __half22float2(*reinterpret_cast<__half2*>(&v.y)); a[2] += f.x; a[3] += f.y;
    f = __half22float2(*reinterpret_cast<__half2*>(&v.z)); a[4] += f.x; a[5] += f.y;
    f = __half22float2(*reinterpret_cast<__half2*>(&v.w)); a[6] += f.x; a[7] += f.y;
    f = __half22float2(*reinterpret_cast<__half2*>(&v4));  a[8] += f.x;
}

__global__ __launch_bounds__(256) void gather_tanh(
    const int* __restrict__ eidx, const __half* __restrict__ yh, float* __restrict__ out)
{
    __shared__ int   sRow[3 * 256];
    __shared__ int   sCol[3 * 256];
    __shared__ float sOut[NOUT * 256];

    const int t  = threadIdx.x;
    const int g0 = blockIdx.x * 256;
    const int e0 = g0 * 3;

#pragma unroll
    for (int p = 0; p < 3; ++p) {
        int e = e0 + t + p * 256;
        sRow[t + p * 256] = eidx[e];
        sCol[t + p * 256] = eidx[NEDGE + e];
    }
    __syncthreads();

    float a[NOUT];
#pragma unroll
    for (int j = 0; j < NOUT; ++j) a[j] = 0.f;

#pragma unroll
    for (int p = 0; p < 3; ++p) {
        {
            const unsigned int* pr =
                reinterpret_cast<const unsigned int*>(yh + (size_t)sRow[3 * t + p] * YH_STRIDE);
            uint4 v = *reinterpret_cast<const uint4*>(pr);   // L0..L7
            unsigned int v4 = pr[4];                         // L8 (+pad)
            acc9(a, v, v4);
        }
        {
            const unsigned int* pc =
                reinterpret_cast<const unsigned int*>(yh + (size_t)sCol[3 * t + p] * YH_STRIDE + 16);
            uint4 v = *reinterpret_cast<const uint4*>(pc);   // R0..R7 (byte offset 32)
            unsigned int v4 = pc[4];                         // R8 (+pad)
            acc9(a, v, v4);
        }
    }

#pragma unroll
    for (int j = 0; j < NOUT; ++j) sOut[t * NOUT + j] = fast_tanh(a[j]);
    __syncthreads();

    float* o = out + (size_t)g0 * NOUT;
#pragma unroll
    for (int j = 0; j < NOUT; ++j) {
        o[t + 256 * j] = sOut[t + 256 * j];
    }
}

extern "C" void kernel_launch(void* const* d_in, const int* in_sizes, int n_in,
                              void* d_out, int out_size, void* d_ws, size_t ws_size,
                              hipStream_t stream) {
    const float* x    = (const float*)d_in[0];   // [60000, 128] fp32
    const float* W    = (const float*)d_in[1];   // [9, 256] fp32
    const int*   eidx = (const int*)d_in[2];     // [2, 960000] int32
    float*       out  = (float*)d_out;           // [320000, 9] fp32
    __half*      yh   = (__half*)d_ws;           // [60000, 32] fp16 scratch (3.84 MB)

    precompute_y<<<(N_ROWS_C + 63) / 64, 256, 0, stream>>>(x, W, yh);
    gather_tanh<<<NGROUP / 256, 256, 0, stream>>>(eidx, yh, out);
}